// Round 7
// baseline (514.981 us; speedup 1.0000x reference)
//
#include <hip/hip_runtime.h>
#include <hip/hip_bf16.h>
#include <cmath>

// Problem constants
#define B_SZ 8
#define L_SZ 2048
#define D_SZ 1024
#define CH 341
#define CP 384               // padded channel dim (4 x 96)
#define LCONV 2046           // L - KERNEL + 1
#define NSEG 512
#define KDIM 3072            // 3 * 1024 folded conv K

#define POOLED_N (B_SZ * NSEG * D_SZ)

typedef _Float16 f16x8 __attribute__((ext_vector_type(8)));
typedef float f32x4 __attribute__((ext_vector_type(4)));

__device__ __forceinline__ void gl_lds16(const void* g, void* l) {
    __builtin_amdgcn_global_load_lds(
        (const __attribute__((address_space(1))) unsigned int*)g,
        (__attribute__((address_space(3))) unsigned int*)l, 16, 0, 0);
}

// ---------------------------------------------------------------------------
// Prep (fused): blocks [0,8192) convert hidden fp32->fp16;
// blocks [8192,12800) convert w1 -> bpack[c][kk*1024+d] (c padded to 384),
// init logits to b2, zero the two scalar outputs.
// ---------------------------------------------------------------------------
__global__ __launch_bounds__(256) void prep_kernel(
        const float* __restrict__ hidden, const float* __restrict__ w1,
        const float* __restrict__ b2,
        _Float16* __restrict__ hid16, _Float16* __restrict__ bpack,
        float* __restrict__ logits, float* __restrict__ out_scalars) {
    if (blockIdx.x < 8192) {
        size_t t = (size_t)blockIdx.x * 256 + threadIdx.x;   // < 2,097,152
        float4 v0 = ((const float4*)hidden)[t * 2];
        float4 v1 = ((const float4*)hidden)[t * 2 + 1];
        f16x8 o;
        o[0] = (_Float16)v0.x; o[1] = (_Float16)v0.y;
        o[2] = (_Float16)v0.z; o[3] = (_Float16)v0.w;
        o[4] = (_Float16)v1.x; o[5] = (_Float16)v1.y;
        o[6] = (_Float16)v1.z; o[7] = (_Float16)v1.w;
        ((f16x8*)hid16)[t] = o;
    } else {
        int idx = (blockIdx.x - 8192) * 256 + threadIdx.x;   // < 384*3072
        int c = idx / KDIM;
        int kp = idx - c * KDIM;
        int kk = kp >> 10, d = kp & 1023;
        float v = (c < CH) ? w1[((size_t)c * 1024 + d) * 3 + kk] : 0.0f;
        bpack[idx] = (_Float16)v;
        if (idx < B_SZ * LCONV) logits[idx] = b2[0];
        if (idx == 0) { out_scalars[0] = 0.0f; out_scalars[1] = 0.0f; }
    }
}

// ---------------------------------------------------------------------------
// fp16 MFMA conv GEMM (r3 backbone, B via direct global loads).
// Per batch: M=2046(l) x N=384(c) x K=3072. A[l][k']=hid_flat[l*1024+k'].
// Tile 128l x 96c, BK=64, 4 waves, wave-tile 64x48 (4x3 16x16x32 frags).
// A staged via global_load_lds in fragment order (16KB, conflict-free);
// B (2.25MB, L2-hot: every mt-block re-reads it) loaded straight to VGPRs
// with per-lane addresses matching the MFMA B layout -> LDS traffic/step
// drops 84KB -> 48KB (the r3 bottleneck per the LDS-BW model).
// Grid (4,16,8) = 512 blocks = 2/CU.
// Fused epilogue: relu(h+b1)*w2 reduced over c, atomicAdd into logits.
// ---------------------------------------------------------------------------
__global__ __launch_bounds__(256, 2) void conv_mfma_kernel(
        const _Float16* __restrict__ hid16, const _Float16* __restrict__ bpack,
        const float* __restrict__ b1, const float* __restrict__ w2,
        float* __restrict__ logits) {
    const int nt = blockIdx.x;           // 0..3
    const int mt = blockIdx.y;           // 0..15
    const int b  = blockIdx.z;
    const int l0 = mt * 128;
    const int n0 = nt * 96;
    const int tid = threadIdx.x;
    const int wave = tid >> 6, lane = tid & 63;
    const int wm = wave & 1, wn = wave >> 1;
    const int quad = lane >> 4, l16 = lane & 15;

    __shared__ __align__(16) char lds[16384];   // A only: 1024 entries x 16B

    const _Float16* hb = hid16 + (size_t)b * L_SZ * D_SZ;

    // A staging: entry f = kc*512 + mf*64 + le ; l = l0+mf*16+(le&15),
    // k = kc*32 + (le>>4)*8. 4 entries per thread.
    const _Float16* pa[4];
    #pragma unroll
    for (int p = 0; p < 4; ++p) {
        int f = p * 256 + tid;
        int kc = f >> 9, mf = (f >> 6) & 7, le = f & 63;
        int l = l0 + mf * 16 + (le & 15);
        if (l > LCONV - 1) l = LCONV - 1;
        pa[p] = hb + (size_t)l * 1024 + kc * 32 + (le >> 4) * 8;
    }
    // B fragment base pointers (per-lane, matches MFMA B operand layout:
    // n = lane&15 within 16-block, k = quad*8 .. +8)
    const _Float16* pbB[3];
    #pragma unroll
    for (int jj = 0; jj < 3; ++jj)
        pbB[jj] = bpack + (size_t)(n0 + wn * 48 + jj * 16 + l16) * KDIM + quad * 8;

    f32x4 acc[4][3] = {};

    for (int s = 0; s < KDIM / 64; ++s) {
        #pragma unroll
        for (int p = 0; p < 4; ++p)
            gl_lds16(pa[p], lds + (p * 256 + wave * 64) * 16);
        #pragma unroll
        for (int p = 0; p < 4; ++p) pa[p] += 64;
        // B loads issued before the barrier: they drain with the gl_lds vmcnt
        f16x8 bb[2][3];
        #pragma unroll
        for (int kc = 0; kc < 2; ++kc)
            #pragma unroll
            for (int jj = 0; jj < 3; ++jj)
                bb[kc][jj] = *(const f16x8*)(pbB[jj] + s * 64 + kc * 32);
        __syncthreads();
        #pragma unroll
        for (int kc = 0; kc < 2; ++kc) {
            f16x8 a[4];
            #pragma unroll
            for (int ii = 0; ii < 4; ++ii)
                a[ii] = *(const f16x8*)(lds + (kc * 512 + (wm * 4 + ii) * 64 + lane) * 16);
            #pragma unroll
            for (int ii = 0; ii < 4; ++ii)
                #pragma unroll
                for (int jj = 0; jj < 3; ++jj)
                    acc[ii][jj] = __builtin_amdgcn_mfma_f32_16x16x32_f16(
                        a[ii], bb[kc][jj], acc[ii][jj], 0, 0, 0);
        }
        __syncthreads();
    }

    // --- epilogue: relu(acc + b1)*w2, reduce over c, atomic into logits ---
    float cb1[3], cw2[3];
    #pragma unroll
    for (int jj = 0; jj < 3; ++jj) {
        int ch = n0 + wn * 48 + jj * 16 + l16;
        bool v = ch < CH;
        cb1[jj] = v ? b1[ch] : 0.0f;
        cw2[jj] = v ? w2[ch] : 0.0f;
    }
    float* red = (float*)lds;   // [128][2]
    #pragma unroll
    for (int ii = 0; ii < 4; ++ii)
        #pragma unroll
        for (int r = 0; r < 4; ++r) {
            float P = 0.0f;
            #pragma unroll
            for (int jj = 0; jj < 3; ++jj) {
                float h = acc[ii][jj][r] + cb1[jj];
                if (h > 0.0f) P += h * cw2[jj];
            }
            P += __shfl_xor(P, 1);
            P += __shfl_xor(P, 2);
            P += __shfl_xor(P, 4);
            P += __shfl_xor(P, 8);
            if (l16 == 0)
                red[(wm * 64 + ii * 16 + quad * 4 + r) * 2 + wn] = P;
        }
    __syncthreads();
    if (tid < 128) {
        int l = l0 + tid;
        if (l < LCONV)
            atomicAdd(&logits[b * LCONV + l], red[tid * 2] + red[tid * 2 + 1]);
    }
}

// ---------------------------------------------------------------------------
// Exact fp32 fixup: fp16-GEMM logit error sigma ~= 0.027, so any
// |logit| < 0.25 (~9 sigma) is recomputed exactly from hidden/w1 in fp32.
// Expected flagged: ~10 positions total.
// ---------------------------------------------------------------------------
__global__ __launch_bounds__(256) void fixup_kernel(
        const float* __restrict__ hidden, const float* __restrict__ w1,
        const float* __restrict__ b1, const float* __restrict__ w2,
        const float* __restrict__ b2, float* __restrict__ logits) {
    const int b = blockIdx.y, l0 = blockIdx.x * 64, tid = threadIdx.x;
    __shared__ float hrow[3 * 1024];
    __shared__ float sred[256];
    __shared__ int flags[64];
    __shared__ int nflag;
    if (tid == 0) nflag = 0;
    __syncthreads();
    if (tid < 64) {
        int l = l0 + tid;
        if (l < LCONV) {
            float v = logits[b * LCONV + l];
            if (fabsf(v) < 0.25f) { int k = atomicAdd(&nflag, 1); flags[k] = l; }
        }
    }
    __syncthreads();
    const int nf = nflag;
    for (int fi = 0; fi < nf; ++fi) {
        const int l = flags[fi];
        for (int t = tid; t < 3072; t += 256)
            hrow[t] = hidden[((size_t)b * L_SZ + l) * 1024 + t];
        __syncthreads();
        float tot = 0.0f;
        for (int c = tid; c < CH; c += 256) {
            const float* wr = w1 + (size_t)c * 3072;
            float dot = 0.0f;
            for (int d = 0; d < 1024; ++d)
                dot += hrow[d] * wr[d * 3] + hrow[1024 + d] * wr[d * 3 + 1]
                     + hrow[2048 + d] * wr[d * 3 + 2];
            float h = dot + b1[c];
            if (h > 0.0f) tot += h * w2[c];
        }
        sred[tid] = tot; __syncthreads();
        for (int off = 128; off > 0; off >>= 1) {
            if (tid < off) sred[tid] += sred[tid + off];
            __syncthreads();
        }
        if (tid == 0) logits[b * LCONV + l] = sred[0] + b2[0];
        __syncthreads();
    }
}

// ---------------------------------------------------------------------------
// Boundary scan: hard bits -> segment starts, short_mask, scalar outputs.
// ---------------------------------------------------------------------------
__global__ void boundary_scan_kernel(const float* __restrict__ logits,
                                     const float* __restrict__ amask,
                                     int* __restrict__ segstart,
                                     float* __restrict__ out_nb,
                                     float* __restrict__ out_tp,
                                     float* __restrict__ short_mask) {
    const int b = blockIdx.x, tid = threadIdx.x;
    __shared__ int sdata[256];
    __shared__ int s_len, s_total;

    int cnt = 0;
    #pragma unroll
    for (int j = 0; j < 8; ++j) {
        int l = tid * 8 + j;
        cnt += (amask[b * L_SZ + l] > 0.5f) ? 1 : 0;
    }
    sdata[tid] = cnt; __syncthreads();
    for (int off = 128; off > 0; off >>= 1) {
        if (tid < off) sdata[tid] += sdata[tid + off];
        __syncthreads();
    }
    if (tid == 0) s_len = sdata[0];
    __syncthreads();
    const int len = s_len;

    int bits[8]; int tsum = 0;
    #pragma unroll
    for (int j = 0; j < 8; ++j) {
        int l = tid * 8 + j;
        int hh = 0;
        if (l >= 2 && l < len) hh = (logits[b * LCONV + (l - 2)] > 0.0f) ? 1 : 0;
        if (len < L_SZ && l == len - 1) hh = 1;
        bits[j] = hh; tsum += hh;
    }
    __syncthreads();
    sdata[tid] = tsum; __syncthreads();
    for (int off = 1; off < 256; off <<= 1) {
        int v = (tid >= off) ? sdata[tid - off] : 0;
        __syncthreads();
        sdata[tid] += v;
        __syncthreads();
    }
    const int texcl = sdata[tid] - tsum;
    if (tid == 255) s_total = sdata[255];
    __syncthreads();
    const int total = s_total;

    for (int s = tid; s <= NSEG; s += 256)
        segstart[b * (NSEG + 1) + s] = (s == 0) ? 0 : len;
    __syncthreads();
    int run = texcl;
    #pragma unroll
    for (int j = 0; j < 8; ++j) {
        int l = tid * 8 + j;
        if (bits[j]) {
            if (run + 1 <= NSEG) segstart[b * (NSEG + 1) + run + 1] = l + 1;
            run++;
        }
    }

    if (tid == 0) {
        atomicAdd(out_nb, (float)total);
        atomicAdd(out_tp, (float)len);
    }
    for (int s = tid; s < NSEG; s += 256)
        short_mask[b * NSEG + s] = (s < total) ? 1.0f : 0.0f;
}

// ---------------------------------------------------------------------------
// Pool: one block per (segment, batch); thread = one float4 of d. Four
// independent accumulator/load chains per iteration hide latency (r1's
// serial-chain failure mode). Empty segments write PE only. No atomics,
// no pre-zeroing, PE fused.
// ---------------------------------------------------------------------------
__global__ __launch_bounds__(256) void pool_kernel(
        const float* __restrict__ hidden, const int* __restrict__ segstart,
        float* __restrict__ pooled) {
    const int s = blockIdx.x, b = blockIdx.y, tid = threadIdx.x;
    const int l0 = segstart[b * (NSEG + 1) + s];
    const int l1 = segstart[b * (NSEG + 1) + s + 1];
    const float4* base = (const float4*)hidden + (size_t)b * L_SZ * 256 + tid;

    float4 a0 = make_float4(0.f, 0.f, 0.f, 0.f), a1 = a0, a2 = a0, a3 = a0;
    int l = l0;
    for (; l + 4 <= l1; l += 4) {
        float4 v0 = base[(size_t)(l + 0) * 256];
        float4 v1 = base[(size_t)(l + 1) * 256];
        float4 v2 = base[(size_t)(l + 2) * 256];
        float4 v3 = base[(size_t)(l + 3) * 256];
        a0.x += v0.x; a0.y += v0.y; a0.z += v0.z; a0.w += v0.w;
        a1.x += v1.x; a1.y += v1.y; a1.z += v1.z; a1.w += v1.w;
        a2.x += v2.x; a2.y += v2.y; a2.z += v2.z; a2.w += v2.w;
        a3.x += v3.x; a3.y += v3.y; a3.z += v3.z; a3.w += v3.w;
    }
    for (; l < l1; ++l) {
        float4 v = base[(size_t)l * 256];
        a0.x += v.x; a0.y += v.y; a0.z += v.z; a0.w += v.w;
    }
    float4 acc;
    acc.x = (a0.x + a1.x) + (a2.x + a3.x);
    acc.y = (a0.y + a1.y) + (a2.y + a3.y);
    acc.z = (a0.z + a1.z) + (a2.z + a3.z);
    acc.w = (a0.w + a1.w) + (a2.w + a3.w);
    const float inv = 1.0f / ((float)(l1 - l0) + 1e-9f);

    const int d0 = tid * 4;
    const float ce = -9.210340371976184f / 512.0f;   // -ln(10000)/512
    const int i = d0 >> 1;
    const float ang0 = (float)s * expf(ce * (float)i);
    const float ang1 = (float)s * expf(ce * (float)(i + 1));
    float4 o;
    o.x = acc.x * inv + sinf(ang0);
    o.y = acc.y * inv + cosf(ang0);
    o.z = acc.z * inv + sinf(ang1);
    o.w = acc.w * inv + cosf(ang1);
    ((float4*)pooled)[(size_t)(b * NSEG + s) * 256 + tid] = o;
}

// ---------------------------------------------------------------------------
extern "C" void kernel_launch(void* const* d_in, const int* in_sizes, int n_in,
                              void* d_out, int out_size, void* d_ws, size_t ws_size,
                              hipStream_t stream) {
    const float* hidden = (const float*)d_in[0];
    const float* amask  = (const float*)d_in[1];
    const float* w1     = (const float*)d_in[2];
    const float* b1     = (const float*)d_in[3];
    const float* w2     = (const float*)d_in[4];
    const float* b2     = (const float*)d_in[5];

    float* out    = (float*)d_out;
    float* pooled = out;
    float* nb     = out + POOLED_N;
    float* smask  = out + POOLED_N + 2;

    const size_t HID_E = (size_t)B_SZ * L_SZ * D_SZ;           // 16,777,216
    const size_t OFF_HID16    = 0;
    const size_t OFF_BPACK    = OFF_HID16 + HID_E * 2;                  // 32 MB
    const size_t OFF_LOGITS   = OFF_BPACK + (size_t)CP * KDIM * 2;      // +2.25 MB
    const size_t OFF_SEGSTART = OFF_LOGITS + (size_t)B_SZ * LCONV * 4;

    _Float16* hid16  = (_Float16*)((char*)d_ws + OFF_HID16);
    _Float16* bpack  = (_Float16*)((char*)d_ws + OFF_BPACK);
    float*    logits = (float*)((char*)d_ws + OFF_LOGITS);
    int*      segst  = (int*)((char*)d_ws + OFF_SEGSTART);

    prep_kernel<<<12800, 256, 0, stream>>>(hidden, w1, b2, hid16, bpack, logits, nb);
    conv_mfma_kernel<<<dim3(4, 16, B_SZ), 256, 0, stream>>>(hid16, bpack, b1, w2, logits);
    fixup_kernel<<<dim3(32, B_SZ), 256, 0, stream>>>(hidden, w1, b1, w2, b2, logits);
    boundary_scan_kernel<<<B_SZ, 256, 0, stream>>>(logits, amask, segst, nb, nb + 1, smask);
    pool_kernel<<<dim3(NSEG, B_SZ), 256, 0, stream>>>(hidden, segst, pooled);
}

// Round 8
// 292.945 us; speedup vs baseline: 1.7579x; 1.7579x over previous
//
#include <hip/hip_runtime.h>
#include <hip/hip_bf16.h>
#include <cmath>

// Problem constants
#define B_SZ 8
#define L_SZ 2048
#define D_SZ 1024
#define CH 341
#define CP 384               // padded channel dim (4 x 96)
#define LCONV 2046           // L - KERNEL + 1
#define NSEG 512
#define KDIM 3072            // 3 * 1024 folded conv K

#define POOLED_N (B_SZ * NSEG * D_SZ)

typedef _Float16 f16x8 __attribute__((ext_vector_type(8)));
typedef float f32x4 __attribute__((ext_vector_type(4)));

__device__ __forceinline__ void gl_lds16(const void* g, void* l) {
    __builtin_amdgcn_global_load_lds(
        (const __attribute__((address_space(1))) unsigned int*)g,
        (__attribute__((address_space(3))) unsigned int*)l, 16, 0, 0);
}

// ---------------------------------------------------------------------------
// Prep (fused): blocks [0,8192) convert hidden fp32->fp16;
// blocks [8192,12800) convert w1 -> bpack[c][kk*1024+d] (c padded to 384),
// init logits to b2, zero the two scalar outputs.
// ---------------------------------------------------------------------------
__global__ __launch_bounds__(256) void prep_kernel(
        const float* __restrict__ hidden, const float* __restrict__ w1,
        const float* __restrict__ b2,
        _Float16* __restrict__ hid16, _Float16* __restrict__ bpack,
        float* __restrict__ logits, float* __restrict__ out_scalars) {
    if (blockIdx.x < 8192) {
        size_t t = (size_t)blockIdx.x * 256 + threadIdx.x;   // < 2,097,152
        float4 v0 = ((const float4*)hidden)[t * 2];
        float4 v1 = ((const float4*)hidden)[t * 2 + 1];
        f16x8 o;
        o[0] = (_Float16)v0.x; o[1] = (_Float16)v0.y;
        o[2] = (_Float16)v0.z; o[3] = (_Float16)v0.w;
        o[4] = (_Float16)v1.x; o[5] = (_Float16)v1.y;
        o[6] = (_Float16)v1.z; o[7] = (_Float16)v1.w;
        ((f16x8*)hid16)[t] = o;
    } else {
        int idx = (blockIdx.x - 8192) * 256 + threadIdx.x;   // < 384*3072
        int c = idx / KDIM;
        int kp = idx - c * KDIM;
        int kk = kp >> 10, d = kp & 1023;
        float v = (c < CH) ? w1[((size_t)c * 1024 + d) * 3 + kk] : 0.0f;
        bpack[idx] = (_Float16)v;
        if (idx < B_SZ * LCONV) logits[idx] = b2[0];
        if (idx == 0) { out_scalars[0] = 0.0f; out_scalars[1] = 0.0f; }
    }
}

// ---------------------------------------------------------------------------
// fp16 MFMA conv GEMM (r7 version: A via global_load_lds fragment-order,
// B direct global->VGPR loads from the L2-hot 2.25MB packed weights).
// Per batch: M=2046(l) x N=384(c) x K=3072. A[l][k']=hid_flat[l*1024+k'].
// Tile 128l x 96c, BK=64, 4 waves, wave-tile 64x48 (4x3 16x16x32 frags).
// Grid (4,16,8) = 512 blocks = 2/CU.
// Fused epilogue: relu(h+b1)*w2 reduced over c, atomicAdd into logits.
// ---------------------------------------------------------------------------
__global__ __launch_bounds__(256, 2) void conv_mfma_kernel(
        const _Float16* __restrict__ hid16, const _Float16* __restrict__ bpack,
        const float* __restrict__ b1, const float* __restrict__ w2,
        float* __restrict__ logits) {
    const int nt = blockIdx.x;           // 0..3
    const int mt = blockIdx.y;           // 0..15
    const int b  = blockIdx.z;
    const int l0 = mt * 128;
    const int n0 = nt * 96;
    const int tid = threadIdx.x;
    const int wave = tid >> 6, lane = tid & 63;
    const int wm = wave & 1, wn = wave >> 1;
    const int quad = lane >> 4, l16 = lane & 15;

    __shared__ __align__(16) char lds[16384];   // A only: 1024 entries x 16B

    const _Float16* hb = hid16 + (size_t)b * L_SZ * D_SZ;

    // A staging: entry f = kc*512 + mf*64 + le ; l = l0+mf*16+(le&15),
    // k = kc*32 + (le>>4)*8. 4 entries per thread.
    const _Float16* pa[4];
    #pragma unroll
    for (int p = 0; p < 4; ++p) {
        int f = p * 256 + tid;
        int kc = f >> 9, mf = (f >> 6) & 7, le = f & 63;
        int l = l0 + mf * 16 + (le & 15);
        if (l > LCONV - 1) l = LCONV - 1;
        pa[p] = hb + (size_t)l * 1024 + kc * 32 + (le >> 4) * 8;
    }
    // B fragment base pointers (per-lane, matches MFMA B operand layout:
    // n = lane&15 within each 16-col block, k = quad*8 .. +8)
    const _Float16* pbB[3];
    #pragma unroll
    for (int jj = 0; jj < 3; ++jj)
        pbB[jj] = bpack + (size_t)(n0 + wn * 48 + jj * 16 + l16) * KDIM + quad * 8;

    f32x4 acc[4][3] = {};

    for (int s = 0; s < KDIM / 64; ++s) {
        #pragma unroll
        for (int p = 0; p < 4; ++p)
            gl_lds16(pa[p], lds + (p * 256 + wave * 64) * 16);
        #pragma unroll
        for (int p = 0; p < 4; ++p) pa[p] += 64;
        // B loads issued before the barrier: they drain with the gl_lds vmcnt
        f16x8 bb[2][3];
        #pragma unroll
        for (int kc = 0; kc < 2; ++kc)
            #pragma unroll
            for (int jj = 0; jj < 3; ++jj)
                bb[kc][jj] = *(const f16x8*)(pbB[jj] + s * 64 + kc * 32);
        __syncthreads();
        #pragma unroll
        for (int kc = 0; kc < 2; ++kc) {
            f16x8 a[4];
            #pragma unroll
            for (int ii = 0; ii < 4; ++ii)
                a[ii] = *(const f16x8*)(lds + (kc * 512 + (wm * 4 + ii) * 64 + lane) * 16);
            #pragma unroll
            for (int ii = 0; ii < 4; ++ii)
                #pragma unroll
                for (int jj = 0; jj < 3; ++jj)
                    acc[ii][jj] = __builtin_amdgcn_mfma_f32_16x16x32_f16(
                        a[ii], bb[kc][jj], acc[ii][jj], 0, 0, 0);
        }
        __syncthreads();
    }

    // --- epilogue: relu(acc + b1)*w2, reduce over c, atomic into logits ---
    float cb1[3], cw2[3];
    #pragma unroll
    for (int jj = 0; jj < 3; ++jj) {
        int ch = n0 + wn * 48 + jj * 16 + l16;
        bool v = ch < CH;
        cb1[jj] = v ? b1[ch] : 0.0f;
        cw2[jj] = v ? w2[ch] : 0.0f;
    }
    float* red = (float*)lds;   // [128][2]
    #pragma unroll
    for (int ii = 0; ii < 4; ++ii)
        #pragma unroll
        for (int r = 0; r < 4; ++r) {
            float P = 0.0f;
            #pragma unroll
            for (int jj = 0; jj < 3; ++jj) {
                float h = acc[ii][jj][r] + cb1[jj];
                if (h > 0.0f) P += h * cw2[jj];
            }
            P += __shfl_xor(P, 1);
            P += __shfl_xor(P, 2);
            P += __shfl_xor(P, 4);
            P += __shfl_xor(P, 8);
            if (l16 == 0)
                red[(wm * 64 + ii * 16 + quad * 4 + r) * 2 + wn] = P;
        }
    __syncthreads();
    if (tid < 128) {
        int l = l0 + tid;
        if (l < LCONV)
            atomicAdd(&logits[b * LCONV + l], red[tid * 2] + red[tid * 2 + 1]);
    }
}

// ---------------------------------------------------------------------------
// Exact fp32 fixup: fp16-GEMM logit error sigma ~= 0.027, so any
// |logit| < 0.25 (~9 sigma) is recomputed exactly from hidden/w1 in fp32.
// Expected flagged: ~10 positions total.
// ---------------------------------------------------------------------------
__global__ __launch_bounds__(256) void fixup_kernel(
        const float* __restrict__ hidden, const float* __restrict__ w1,
        const float* __restrict__ b1, const float* __restrict__ w2,
        const float* __restrict__ b2, float* __restrict__ logits) {
    const int b = blockIdx.y, l0 = blockIdx.x * 64, tid = threadIdx.x;
    __shared__ float hrow[3 * 1024];
    __shared__ float sred[256];
    __shared__ int flags[64];
    __shared__ int nflag;
    if (tid == 0) nflag = 0;
    __syncthreads();
    if (tid < 64) {
        int l = l0 + tid;
        if (l < LCONV) {
            float v = logits[b * LCONV + l];
            if (fabsf(v) < 0.25f) { int k = atomicAdd(&nflag, 1); flags[k] = l; }
        }
    }
    __syncthreads();
    const int nf = nflag;
    for (int fi = 0; fi < nf; ++fi) {
        const int l = flags[fi];
        for (int t = tid; t < 3072; t += 256)
            hrow[t] = hidden[((size_t)b * L_SZ + l) * 1024 + t];
        __syncthreads();
        float tot = 0.0f;
        for (int c = tid; c < CH; c += 256) {
            const float* wr = w1 + (size_t)c * 3072;
            float dot = 0.0f;
            for (int d = 0; d < 1024; ++d)
                dot += hrow[d] * wr[d * 3] + hrow[1024 + d] * wr[d * 3 + 1]
                     + hrow[2048 + d] * wr[d * 3 + 2];
            float h = dot + b1[c];
            if (h > 0.0f) tot += h * w2[c];
        }
        sred[tid] = tot; __syncthreads();
        for (int off = 128; off > 0; off >>= 1) {
            if (tid < off) sred[tid] += sred[tid + off];
            __syncthreads();
        }
        if (tid == 0) logits[b * LCONV + l] = sred[0] + b2[0];
        __syncthreads();
    }
}

// ---------------------------------------------------------------------------
// Boundary scan: hard bits, segment starts, per-token segment ids,
// short_mask, scalar outputs.
// ---------------------------------------------------------------------------
__global__ void boundary_scan_kernel(const float* __restrict__ logits,
                                     const float* __restrict__ amask,
                                     int* __restrict__ segstart,
                                     int* __restrict__ segid,
                                     float* __restrict__ out_nb,
                                     float* __restrict__ out_tp,
                                     float* __restrict__ short_mask) {
    const int b = blockIdx.x, tid = threadIdx.x;
    __shared__ int sdata[256];
    __shared__ int s_len, s_total;

    int cnt = 0;
    #pragma unroll
    for (int j = 0; j < 8; ++j) {
        int l = tid * 8 + j;
        cnt += (amask[b * L_SZ + l] > 0.5f) ? 1 : 0;
    }
    sdata[tid] = cnt; __syncthreads();
    for (int off = 128; off > 0; off >>= 1) {
        if (tid < off) sdata[tid] += sdata[tid + off];
        __syncthreads();
    }
    if (tid == 0) s_len = sdata[0];
    __syncthreads();
    const int len = s_len;

    int bits[8]; int tsum = 0;
    #pragma unroll
    for (int j = 0; j < 8; ++j) {
        int l = tid * 8 + j;
        int hh = 0;
        if (l >= 2 && l < len) hh = (logits[b * LCONV + (l - 2)] > 0.0f) ? 1 : 0;
        if (len < L_SZ && l == len - 1) hh = 1;
        bits[j] = hh; tsum += hh;
    }
    __syncthreads();
    sdata[tid] = tsum; __syncthreads();
    for (int off = 1; off < 256; off <<= 1) {
        int v = (tid >= off) ? sdata[tid - off] : 0;
        __syncthreads();
        sdata[tid] += v;
        __syncthreads();
    }
    const int texcl = sdata[tid] - tsum;
    if (tid == 255) s_total = sdata[255];
    __syncthreads();
    const int total = s_total;

    for (int s = tid; s <= NSEG; s += 256)
        segstart[b * (NSEG + 1) + s] = (s == 0) ? 0 : len;
    __syncthreads();
    int run = texcl;
    #pragma unroll
    for (int j = 0; j < 8; ++j) {
        int l = tid * 8 + j;
        int sv = -1;
        if (l < len && run < NSEG) sv = run;
        segid[b * L_SZ + l] = sv;
        if (bits[j]) {
            if (run + 1 <= NSEG) segstart[b * (NSEG + 1) + run + 1] = l + 1;
            run++;
        }
    }

    if (tid == 0) {
        atomicAdd(out_nb, (float)total);
        atomicAdd(out_tp, (float)len);
    }
    for (int s = tid; s < NSEG; s += 256)
        short_mask[b * NSEG + s] = (s < total) ? 1.0f : 0.0f;
}

// ---------------------------------------------------------------------------
// Pool accumulate (r2/r3-proven, load-balanced): 16-token chunks, thread =
// one float4 of d over the chunk, run-accumulate in registers, atomic flush
// per segment run. Grid (128,8) = 1024 blocks x 256 threads.
// ---------------------------------------------------------------------------
__global__ __launch_bounds__(256) void pool_accum_kernel(
        const float* __restrict__ hidden, const int* __restrict__ segid,
        float* __restrict__ pooled) {
    const int chunk = blockIdx.x, b = blockIdx.y;
    const int tid = threadIdx.x;
    const int d0 = tid * 4;
    const int lbase = chunk * 16;
    const float* hb = hidden + (size_t)b * L_SZ * D_SZ + d0;
    const int* sg = segid + b * L_SZ + lbase;
    float4 acc = make_float4(0.f, 0.f, 0.f, 0.f);
    int cur = -1;
    #pragma unroll
    for (int t = 0; t < 16; ++t) {
        int sid = sg[t];
        if (sid != cur) {
            if (cur >= 0) {
                float* dst = pooled + ((size_t)(b * NSEG + cur)) * D_SZ + d0;
                atomicAdd(dst + 0, acc.x); atomicAdd(dst + 1, acc.y);
                atomicAdd(dst + 2, acc.z); atomicAdd(dst + 3, acc.w);
            }
            acc = make_float4(0.f, 0.f, 0.f, 0.f);
            cur = sid;
        }
        if (sid >= 0) {
            float4 v = *(const float4*)(hb + (size_t)(lbase + t) * D_SZ);
            acc.x += v.x; acc.y += v.y; acc.z += v.z; acc.w += v.w;
        }
    }
    if (cur >= 0) {
        float* dst = pooled + ((size_t)(b * NSEG + cur)) * D_SZ + d0;
        atomicAdd(dst + 0, acc.x); atomicAdd(dst + 1, acc.y);
        atomicAdd(dst + 2, acc.z); atomicAdd(dst + 3, acc.w);
    }
}

// ---------------------------------------------------------------------------
// Pool finalize: divide by count, add sinusoidal PE.
// ---------------------------------------------------------------------------
__global__ __launch_bounds__(256) void pool_final_kernel(
        float* __restrict__ pooled, const int* __restrict__ segstart) {
    const int s = blockIdx.x, b = blockIdx.y, tid = threadIdx.x;
    const int l0 = segstart[b * (NSEG + 1) + s];
    const int l1 = segstart[b * (NSEG + 1) + s + 1];
    const float inv = 1.0f / ((float)(l1 - l0) + 1e-9f);
    const int d0 = tid * 4;
    size_t o = ((size_t)(b * NSEG + s)) * D_SZ + d0;
    float4 v = *(float4*)(pooled + o);
    const float ce = -9.210340371976184f / 512.0f;   // -ln(10000)/512
    const int i = d0 >> 1;
    const float a0 = (float)s * expf(ce * (float)i);
    const float a1 = (float)s * expf(ce * (float)(i + 1));
    float4 out;
    out.x = v.x * inv + sinf(a0);
    out.y = v.y * inv + cosf(a0);
    out.z = v.z * inv + sinf(a1);
    out.w = v.w * inv + cosf(a1);
    *(float4*)(pooled + o) = out;
}

// ---------------------------------------------------------------------------
extern "C" void kernel_launch(void* const* d_in, const int* in_sizes, int n_in,
                              void* d_out, int out_size, void* d_ws, size_t ws_size,
                              hipStream_t stream) {
    const float* hidden = (const float*)d_in[0];
    const float* amask  = (const float*)d_in[1];
    const float* w1     = (const float*)d_in[2];
    const float* b1     = (const float*)d_in[3];
    const float* w2     = (const float*)d_in[4];
    const float* b2     = (const float*)d_in[5];

    float* out    = (float*)d_out;
    float* pooled = out;
    float* nb     = out + POOLED_N;
    float* smask  = out + POOLED_N + 2;

    // zero pooled (atomics accumulate into it); scalars zeroed by prep
    hipMemsetAsync(pooled, 0, (size_t)POOLED_N * sizeof(float), stream);

    const size_t HID_E = (size_t)B_SZ * L_SZ * D_SZ;           // 16,777,216
    const size_t OFF_HID16    = 0;
    const size_t OFF_BPACK    = OFF_HID16 + HID_E * 2;                  // 32 MB
    const size_t OFF_LOGITS   = OFF_BPACK + (size_t)CP * KDIM * 2;      // +2.25 MB
    const size_t OFF_SEGSTART = OFF_LOGITS + (size_t)B_SZ * LCONV * 4;
    const size_t OFF_SEGID    = OFF_SEGSTART + (size_t)B_SZ * (NSEG + 1) * 4;

    _Float16* hid16  = (_Float16*)((char*)d_ws + OFF_HID16);
    _Float16* bpack  = (_Float16*)((char*)d_ws + OFF_BPACK);
    float*    logits = (float*)((char*)d_ws + OFF_LOGITS);
    int*      segst  = (int*)((char*)d_ws + OFF_SEGSTART);
    int*      segid  = (int*)((char*)d_ws + OFF_SEGID);

    prep_kernel<<<12800, 256, 0, stream>>>(hidden, w1, b2, hid16, bpack, logits, nb);
    conv_mfma_kernel<<<dim3(4, 16, B_SZ), 256, 0, stream>>>(hid16, bpack, b1, w2, logits);
    fixup_kernel<<<dim3(32, B_SZ), 256, 0, stream>>>(hidden, w1, b1, w2, b2, logits);
    boundary_scan_kernel<<<B_SZ, 256, 0, stream>>>(logits, amask, segst, segid, nb, nb + 1, smask);
    pool_accum_kernel<<<dim3(128, B_SZ), 256, 0, stream>>>(hidden, segid, pooled);
    pool_final_kernel<<<dim3(NSEG, B_SZ), 256, 0, stream>>>(pooled, segst);
}